// Round 2
// baseline (4253.666 us; speedup 1.0000x reference)
//
#include <hip/hip_runtime.h>
#include <cstdint>
#include <cstddef>

typedef float f32x4 __attribute__((ext_vector_type(4)));
typedef short s16x8 __attribute__((ext_vector_type(8)));
typedef unsigned short u16x4 __attribute__((ext_vector_type(4)));

#define T_LEN 256
#define B_SZ  128

__device__ __forceinline__ float bf2f(unsigned short u){
  union { unsigned int i; float f; } v; v.i = ((unsigned int)u) << 16; return v.f;
}
__device__ __forceinline__ unsigned short f2bf(float f){
  union { float f; unsigned int i; } v; v.f = f;
  return (unsigned short)((v.i + 0x7FFFu + ((v.i >> 16) & 1u)) >> 16);
}
__device__ __forceinline__ float fast_sigmoid(float x){
  return 1.0f / (1.0f + __builtin_amdgcn_exp2f(-1.44269504088896341f * x));
}
__device__ __forceinline__ float fast_tanh(float x){
  return 1.0f - 2.0f / (1.0f + __builtin_amdgcn_exp2f(2.88539008177792681f * x));
}

// ---------------------------------------------------------------------------
// prep: cast/pad weights to bf16, build fused bias (b_ih + b_hh for r,z gates)
// ---------------------------------------------------------------------------
__global__ void prep_kernel(const float* __restrict__ w_ih0, const float* __restrict__ w_hh0,
                            const float* __restrict__ b_ih0, const float* __restrict__ b_hh0,
                            const float* __restrict__ w_ih,  const float* __restrict__ w_hh,
                            const float* __restrict__ b_ih,  const float* __restrict__ b_hh,
                            unsigned short* __restrict__ wih0b, unsigned short* __restrict__ wihb,
                            unsigned short* __restrict__ whhb,  float* __restrict__ bihc){
  const int S1 = 2*768*320;     // 491520
  const int S2 = 2*2*768*512;   // 1572864
  const int S3 = 6*768*256;     // 1179648
  const int S4 = 3*1536;        // 4608
  int idx = blockIdx.x * 256 + threadIdx.x;
  if (idx < S1){
    int k = idx % 320, r = idx / 320;              // r = dir*768 + g
    wih0b[idx] = (k < 300) ? f2bf(w_ih0[r*300 + k]) : (unsigned short)0;
  } else if (idx < S1 + S2){
    int i = idx - S1; wihb[i] = f2bf(w_ih[i]);     // layouts match flat
  } else if (idx < S1 + S2 + S3){
    int i = idx - S1 - S2;
    const int L0 = 2*768*256;
    whhb[i] = f2bf(i < L0 ? w_hh0[i] : w_hh[i - L0]);
  } else if (idx < S1 + S2 + S3 + S4){
    int i = idx - S1 - S2 - S3;
    int l = i / 1536, n = i % 1536, g = n % 768;
    float v = (l == 0) ? b_ih0[n] : b_ih[(l-1)*1536 + n];
    if (g < 512) v += (l == 0) ? b_hh0[n] : b_hh[(l-1)*1536 + n];  // fold r,z b_hh
    bihc[i] = v;
  }
}

// ---------------------------------------------------------------------------
// gather: x0[t*128+b][0:320] = bf16(emb[overview[b][t]]), zero-padded 300->320
// ---------------------------------------------------------------------------
__global__ void gather_kernel(const int* __restrict__ overview, const float* __restrict__ emb,
                              unsigned short* __restrict__ x0){
  const int m = blockIdx.x;              // t*128 + b
  const int t = m >> 7, b = m & 127;
  const int row = overview[b * T_LEN + t];
  const float* src = emb + (size_t)row * 300;
  unsigned short* dst = x0 + (size_t)m * 320;
  for (int i = threadIdx.x; i < 80; i += 64){
    u16x4 o;
    if (i < 75){
      const f32x4 v = *(const f32x4*)(src + i*4);
      o[0] = f2bf(v[0]); o[1] = f2bf(v[1]); o[2] = f2bf(v[2]); o[3] = f2bf(v[3]);
    } else { o[0] = o[1] = o[2] = o[3] = 0; }
    *(u16x4*)(dst + i*4) = o;
  }
}

// ---------------------------------------------------------------------------
// gemm_xg: xg[t][dir][b][g] = bf16( A[m]·Bw[n] + bias[n] ),  m = t*128+b, n = dir*768+g
// ---------------------------------------------------------------------------
__global__ __launch_bounds__(256, 2) void gemm_xg(
    const unsigned short* __restrict__ A, const unsigned short* __restrict__ Bw,
    const float* __restrict__ bias, unsigned short* __restrict__ xg, const int K){
  __shared__ unsigned short a_t[128*40];   // +8 pad per row: conflict-free b128 reads
  __shared__ unsigned short b_t[128*40];
  const int tid = threadIdx.x;
  const int lane = tid & 63, wv = tid >> 6;
  const int l15 = lane & 15, quad = lane >> 4;
  const int m0 = blockIdx.x * 128, n0 = blockIdx.y * 128;
  const int mW = (wv >> 1) * 64, nW = (wv & 1) * 64;
  const int r0 = tid >> 2, c = (tid & 3) * 8;

  f32x4 acc[4][4];
#pragma unroll
  for (int i = 0; i < 4; ++i)
#pragma unroll
    for (int j = 0; j < 4; ++j) acc[i][j] = (f32x4){0.f,0.f,0.f,0.f};

  for (int kk = 0; kk < K; kk += 32){
    __syncthreads();
#pragma unroll
    for (int h = 0; h < 128; h += 64){
      *(s16x8*)&a_t[(r0+h)*40 + c] = *(const s16x8*)(A  + (size_t)(m0+r0+h)*K + kk + c);
      *(s16x8*)&b_t[(r0+h)*40 + c] = *(const s16x8*)(Bw + (size_t)(n0+r0+h)*K + kk + c);
    }
    __syncthreads();
    s16x8 af[4], bf[4];
#pragma unroll
    for (int i = 0; i < 4; ++i){
      af[i] = *(const s16x8*)&a_t[(mW + i*16 + l15)*40 + quad*8];
      bf[i] = *(const s16x8*)&b_t[(nW + i*16 + l15)*40 + quad*8];
    }
#pragma unroll
    for (int i = 0; i < 4; ++i)
#pragma unroll
      for (int j = 0; j < 4; ++j)
        acc[i][j] = __builtin_amdgcn_mfma_f32_16x16x32_bf16(af[i], bf[j], acc[i][j], 0, 0, 0);
  }

#pragma unroll
  for (int j = 0; j < 4; ++j){
    const int n = n0 + nW + j*16 + l15;
    const float bv = bias[n];
    const int dir = (n >= 768) ? 1 : 0;
    const int g = n - dir*768;
#pragma unroll
    for (int i = 0; i < 4; ++i){
      const int mbase = m0 + mW + i*16 + quad*4;
#pragma unroll
      for (int r = 0; r < 4; ++r){
        const int m = mbase + r;
        const int t = m >> 7, b = m & 127;
        xg[((size_t)(t*2 + dir)*128 + b) * 768 + g] = f2bf(acc[i][j][r] + bv);
      }
    }
  }
}

// ---------------------------------------------------------------------------
// rec_kernel v2: 1024 threads = 16 waves (4/SIMD). One block per (16-batch
// group, dir). Wave wv owns j-slice [wv*16, wv*16+16) and its 3 gate tiles
// (r,z,n) with all W_hh fragments in VGPRs (3*8*4 = 96 VGPR/wave).
// h_lds double-buffered -> ONE barrier per step. xg double-buffered in LDS.
// grid = 16: blockIdx = bg(0..7) | dir<<3
// ---------------------------------------------------------------------------
#define HSTR 264   // h_lds row stride (shorts): 132 dwords == 4 mod 32, uniform banks
#define XSTR 776   // xg_lds row stride (shorts): 388 dwords == 4 mod 32

__global__ __launch_bounds__(1024, 1) void rec_kernel(
    const unsigned short* __restrict__ xg,   // [T][2][128][768] bf16
    const unsigned short* __restrict__ whh2, // [2][768][256] bf16 (this layer)
    const float* __restrict__ bhh2,          // [2][768] f32 (this layer)
    unsigned short* __restrict__ y){         // [T][128][512] bf16
  extern __shared__ unsigned short sm[];
  unsigned short* h_lds  = sm;                       // [2][16][HSTR]
  unsigned short* xg_lds = sm + 2*16*HSTR;           // [2][16][XSTR]

  const int tid  = threadIdx.x;
  const int lane = tid & 63;
  const int wv   = tid >> 6;          // 0..15 = j-slice
  const int l15  = lane & 15;         // batch row within group
  const int quad = lane >> 4;
  const int bg   = blockIdx.x & 7;
  const int dir  = blockIdx.x >> 3;
  const int bgBase = bg * 16;

  const unsigned short* whh = whh2 + dir * (768*256);
  // n-gate b_hh for this thread's 4 j values
  const f32x4 bn = *(const f32x4*)(bhh2 + dir*768 + 512 + wv*16 + quad*4);

  // zero h buffer 0 (read at step 0)
  for (int i = tid; i < 16*HSTR; i += 1024) h_lds[i] = 0;

  // W_hh fragments: tile gt (r,z,n), rows g = gt*256 + wv*16 + l15, k frag
  s16x8 wreg[3][8];
#pragma unroll
  for (int gt = 0; gt < 3; ++gt){
    const unsigned short* src = whh + (size_t)(gt*256 + wv*16 + l15) * 256;
#pragma unroll
    for (int ks = 0; ks < 8; ++ks)
      wreg[gt][ks] = *(const s16x8*)(src + ks*32 + quad*8);
  }

  float hreg[4];
#pragma unroll
  for (int i = 0; i < 4; ++i) hreg[i] = 0.0f;

  // xg staging: 16 rows x 768 cols = 1536 s16x8 chunks; thread does e and e+1024
  const int e0 = tid;
  const int r0 = e0 / 96, c0 = (e0 - r0*96) * 8;
  const int e1 = tid + 1024;
  const int r1 = e1 / 96, c1 = (e1 - r1*96) * 8;
  const bool has2 = (tid < 512);

  {  // pre-stage step 0 into xbuf 0
    const int t0 = dir ? (T_LEN - 1) : 0;
    const unsigned short* src = xg + ((size_t)(t0*2 + dir)*128 + bgBase) * 768;
    unsigned short* dst = xg_lds;
    *(s16x8*)(dst + r0*XSTR + c0) = *(const s16x8*)(src + r0*768 + c0);
    if (has2) *(s16x8*)(dst + r1*XSTR + c1) = *(const s16x8*)(src + r1*768 + c1);
  }
  __syncthreads();

  for (int s = 0; s < T_LEN; ++s){
    const int t = dir ? (T_LEN - 1 - s) : s;
    unsigned short* hb_cur = h_lds + (s & 1) * (16*HSTR);
    unsigned short* hb_nxt = h_lds + ((s+1) & 1) * (16*HSTR);
    unsigned short* xb_cur = xg_lds + (s & 1) * (16*XSTR);
    unsigned short* xb_nxt = xg_lds + ((s+1) & 1) * (16*XSTR);

    // (a) issue next-step xg global loads early (hide under MFMA)
    s16x8 stg0, stg1;
    const bool do_stage = (s + 1 < T_LEN);
    if (do_stage){
      const int t1 = dir ? (T_LEN - 2 - s) : (s + 1);
      const unsigned short* src = xg + ((size_t)(t1*2 + dir)*128 + bgBase) * 768;
      stg0 = *(const s16x8*)(src + r0*768 + c0);
      if (has2) stg1 = *(const s16x8*)(src + r1*768 + c1);
    }

    // (b) B-frags: h[b=l15][k], shared across all 16 waves
    s16x8 bfr[8];
#pragma unroll
    for (int ks = 0; ks < 8; ++ks)
      bfr[ks] = *(const s16x8*)(hb_cur + l15*HSTR + ks*32 + quad*8);

    f32x4 acc[3];
#pragma unroll
    for (int gt = 0; gt < 3; ++gt) acc[gt] = (f32x4){0.f,0.f,0.f,0.f};
#pragma unroll
    for (int gt = 0; gt < 3; ++gt)
#pragma unroll
      for (int ks = 0; ks < 8; ++ks)
        acc[gt] = __builtin_amdgcn_mfma_f32_16x16x32_bf16(wreg[gt][ks], bfr[ks], acc[gt], 0, 0, 0);

    // (c) park staged xg into next buffer
    if (do_stage){
      *(s16x8*)(xb_nxt + r0*XSTR + c0) = stg0;
      if (has2) *(s16x8*)(xb_nxt + r1*XSTR + c1) = stg1;
    }

    // (d) gates: this thread = (b=l15, j = wv*16 + quad*4 + r)
    const int cbase = l15*XSTR + wv*16 + quad*4;
    u16x4 xr4 = *(const u16x4*)(xb_cur + cbase);
    u16x4 xz4 = *(const u16x4*)(xb_cur + cbase + 256);
    u16x4 xn4 = *(const u16x4*)(xb_cur + cbase + 512);
    u16x4 hw;
#pragma unroll
    for (int r = 0; r < 4; ++r){
      float rr = fast_sigmoid(bf2f(xr4[r]) + acc[0][r]);
      float zz = fast_sigmoid(bf2f(xz4[r]) + acc[1][r]);
      float nn = fast_tanh(bf2f(xn4[r]) + rr * (acc[2][r] + bn[r]));
      float hv = (1.0f - zz) * nn + zz * hreg[r];
      hreg[r] = hv;
      hw[r] = f2bf(hv);
    }
    *(u16x4*)(hb_nxt + l15*HSTR + wv*16 + quad*4) = hw;
    *(u16x4*)(y + ((size_t)t*128 + bgBase + l15) * 512 + dir*256 + wv*16 + quad*4) = hw;

    __syncthreads();   // h writes + xg park visible; WAR safe via double buffers
  }
}

// ---------------------------------------------------------------------------
// final: out[b][o] = sum_j y[T-1][b][j] * lin_w[o][j] + lin_b[o]
// ---------------------------------------------------------------------------
__global__ void final_kernel(const unsigned short* __restrict__ y, const float* __restrict__ lin_w,
                             const float* __restrict__ lin_b, float* __restrict__ out){
  const int b = blockIdx.x, lane = threadIdx.x;  // 64 threads
  s16x8 hv = *(const s16x8*)(y + ((size_t)((T_LEN-1)*128 + b)) * 512 + lane*8);
  float hf[8];
#pragma unroll
  for (int i = 0; i < 8; ++i) hf[i] = bf2f((unsigned short)hv[i]);
  float p[18];
#pragma unroll
  for (int o = 0; o < 18; ++o) p[o] = 0.0f;
#pragma unroll
  for (int i = 0; i < 8; ++i)
#pragma unroll
    for (int o = 0; o < 18; ++o) p[o] += hf[i] * lin_w[o*512 + lane*8 + i];
#pragma unroll
  for (int o = 0; o < 18; ++o){
    float v = p[o];
    for (int off = 32; off > 0; off >>= 1) v += __shfl_xor(v, off, 64);
    if (lane == 0) out[b*18 + o] = v + lin_b[o];
  }
}

// ---------------------------------------------------------------------------
extern "C" void kernel_launch(void* const* d_in, const int* in_sizes, int n_in,
                              void* d_out, int out_size, void* d_ws, size_t ws_size,
                              hipStream_t stream){
  const int*   overview = (const int*)  d_in[0];
  const float* emb   = (const float*)d_in[1];
  const float* w_ih0 = (const float*)d_in[2];
  const float* w_hh0 = (const float*)d_in[3];
  const float* b_ih0 = (const float*)d_in[4];
  const float* b_hh0 = (const float*)d_in[5];
  const float* w_ih  = (const float*)d_in[6];
  const float* w_hh  = (const float*)d_in[7];
  const float* b_ih  = (const float*)d_in[8];
  const float* b_hh  = (const float*)d_in[9];
  const float* lin_w = (const float*)d_in[10];
  const float* lin_b = (const float*)d_in[11];
  float* out = (float*)d_out;

  char* ws = (char*)d_ws;
  size_t off = 0;
  auto alloc = [&](size_t bytes) -> char* {
    char* p = ws + off; off += (bytes + 511) & ~(size_t)511; return p;
  };
  unsigned short* x0    = (unsigned short*)alloc((size_t)32768*320*2);
  unsigned short* wih0b = (unsigned short*)alloc((size_t)2*768*320*2);
  unsigned short* wihb  = (unsigned short*)alloc((size_t)2*2*768*512*2);
  unsigned short* whhb  = (unsigned short*)alloc((size_t)6*768*256*2);
  float*          bihc  = (float*)         alloc((size_t)3*1536*4);
  unsigned short* xgb   = (unsigned short*)alloc((size_t)256*2*128*768*2);
  unsigned short* ya    = (unsigned short*)alloc((size_t)32768*512*2);
  unsigned short* yb    = (unsigned short*)alloc((size_t)32768*512*2);

  const size_t REC_LDS = (size_t)(2*16*HSTR + 2*16*XSTR) * 2;  // 66,560 B
  hipFuncSetAttribute((const void*)rec_kernel,
                      hipFuncAttributeMaxDynamicSharedMemorySize, (int)REC_LDS);

  prep_kernel<<<dim3(12690), 256, 0, stream>>>(w_ih0, w_hh0, b_ih0, b_hh0,
                                               w_ih, w_hh, b_ih, b_hh,
                                               wih0b, wihb, whhb, bihc);
  gather_kernel<<<dim3(32768), 64, 0, stream>>>(overview, emb, x0);

  // layer 0
  gemm_xg<<<dim3(256, 12), 256, 0, stream>>>(x0, wih0b, bihc, xgb, 320);
  rec_kernel<<<dim3(16), 1024, REC_LDS, stream>>>(xgb, whhb, b_hh0, ya);
  // layer 1
  gemm_xg<<<dim3(256, 12), 256, 0, stream>>>(ya, wihb, bihc + 1536, xgb, 512);
  rec_kernel<<<dim3(16), 1024, REC_LDS, stream>>>(xgb, whhb + 2*768*256, b_hh, yb);
  // layer 2
  gemm_xg<<<dim3(256, 12), 256, 0, stream>>>(yb, wihb + (size_t)2*768*512, bihc + 2*1536, xgb, 512);
  rec_kernel<<<dim3(16), 1024, REC_LDS, stream>>>(xgb, whhb + 4*768*256, b_hh + 1536, ya);

  final_kernel<<<dim3(128), 64, 0, stream>>>(ya, lin_w, lin_b, out);
}